// Round 3
// baseline (102.942 us; speedup 1.0000x reference)
//
#include <hip/hip_runtime.h>
#include <hip/hip_bf16.h>

// Quanvolution classifier, round 3: fused sim+head.
//
// Algebra (validated rounds 1-2): variational circuit is data-independent =>
// U (16x16 complex) fixed. Encoder state s = p (x) q (real product state).
//   e_w = s^T M_w s,  M_w = Re(U^dag Z_w U),
//   e_w = sum_{a,b in 10} C_w[a][b] P_a Q_b   (pair-product folding)
// Kernel 1 builds C (400 floats) in d_ws. Kernel 2 (one block per sample)
// computes all 196 patches, dots against W rows, block-reduces 10 logits,
// log-softmax, writes out — feats never touch memory.
//
// Wire convention: wire 0 = MSB; i = 4*jp + jq, s[i] = p[jp]*q[jq],
// p = (c0c1, c0s1, s0c1, s0s1), q = (c2c3, c2s3, s2c3, s2s3).

#define NPATCH 196

// ---------------- kernel 1: vparams -> U -> M_w -> C (400 floats) --------
__global__ void qc_build_C(const float* __restrict__ vp,
                           float* __restrict__ Cout) {
  __shared__ float Ur[16][16];   // [i][j]
  __shared__ float Ui[16][16];
  __shared__ float M[4][16][16];
  int t = threadIdx.x;

  if (t < 16) {
    float sr[16], si[16];
#pragma unroll
    for (int i = 0; i < 16; ++i) { sr[i] = 0.f; si[i] = 0.f; }
    sr[t] = 1.f;

    for (int l = 0; l < 3; ++l) {
#pragma unroll
      for (int w = 0; w < 4; ++w) {
        float thy = vp[l * 8 + (w % 8)];
        float thz = vp[l * 8 + ((w + 1) % 8)];
        float cy, sy, cz, sz;
        __sincosf(0.5f * thy, &sy, &cy);
        __sincosf(0.5f * thz, &sz, &cz);
        const int bit = 8 >> w;
        // RY
#pragma unroll
        for (int i = 0; i < 16; ++i) {
          if (!(i & bit)) {
            int i1 = i | bit;
            float a0r = sr[i], a0i = si[i], a1r = sr[i1], a1i = si[i1];
            sr[i]  = cy * a0r - sy * a1r;  si[i]  = cy * a0i - sy * a1i;
            sr[i1] = sy * a0r + cy * a1r;  si[i1] = sy * a0i + cy * a1i;
          }
        }
        // RZ: amp0 *= e^{-i thz/2}, amp1 *= e^{+i thz/2}
#pragma unroll
        for (int i = 0; i < 16; ++i) {
          float r = sr[i], m = si[i];
          if (i & bit) { sr[i] = r * cz - m * sz; si[i] = m * cz + r * sz; }
          else         { sr[i] = r * cz + m * sz; si[i] = m * cz - r * sz; }
        }
      }
      // CX ring
#pragma unroll
      for (int w = 0; w < 4; ++w) {
        const int cbit = 8 >> w;
        const int tbit = 8 >> ((w + 1) & 3);
#pragma unroll
        for (int i = 0; i < 16; ++i) {
          if ((i & cbit) && !(i & tbit)) {
            int i1 = i | tbit;
            float tr = sr[i], ti = si[i];
            sr[i] = sr[i1]; si[i] = si[i1];
            sr[i1] = tr;    si[i1] = ti;
          }
        }
      }
    }
#pragma unroll
    for (int i = 0; i < 16; ++i) { Ur[i][t] = sr[i]; Ui[i][t] = si[i]; }
  }
  __syncthreads();

  // M_w[r][c] = sum_i sgn_w(i) * (Ur[i][r]Ur[i][c] + Ui[i][r]Ui[i][c])
  for (int e = t; e < 1024; e += 64) {
    int w = e >> 8, r = (e >> 4) & 15, c = e & 15;
    float acc = 0.f;
#pragma unroll
    for (int i = 0; i < 16; ++i) {
      float sgn = ((i >> (3 - w)) & 1) ? -1.f : 1.f;
      acc += sgn * (Ur[i][r] * Ur[i][c] + Ui[i][r] * Ui[i][c]);
    }
    M[w][r][c] = acc;
  }
  __syncthreads();

  const int pj1[10] = {0, 0, 0, 0, 1, 1, 1, 2, 2, 3};
  const int pj2[10] = {0, 1, 2, 3, 1, 2, 3, 2, 3, 3};
  for (int e = t; e < 400; e += 64) {
    int w = e / 100;
    int rem = e - w * 100;
    int a = rem / 10;
    int bq = rem - a * 10;
    int j1 = pj1[a], j2 = pj2[a], k1 = pj1[bq], k2 = pj2[bq];
    float v = M[w][4 * j1 + k1][4 * j2 + k2];
    if (k1 != k2) v += M[w][4 * j1 + k2][4 * j2 + k1];
    if (j1 != j2) {
      v += M[w][4 * j2 + k1][4 * j1 + k2];
      if (k1 != k2) v += M[w][4 * j2 + k2][4 * j1 + k1];
    }
    Cout[e] = v;
  }
}

// ---------------- kernel 2: fused sim + head -----------------------------
// One block per sample; thread p (p<196) = one patch. C is wave-uniform ->
// scalar loads. W4[c*196+p] is lane-consecutive -> coalesced; W (31 KB) is
// L1/L2-resident across the 16 blocks/CU.
__global__ __launch_bounds__(256) void qc_fused(const float* __restrict__ x,
                                                const float* __restrict__ C,
                                                const float4* __restrict__ W4,
                                                const float* __restrict__ bias,
                                                float* __restrict__ out) {
  int b = blockIdx.x;
  int p = threadIdx.x;

  float lg[10];
#pragma unroll
  for (int c = 0; c < 10; ++c) lg[c] = 0.f;

  if (p < NPATCH) {
    int pr = p / 14;
    int pc = p - pr * 14;
    const float* xb = x + (size_t)b * 784;
    float2 top = *(const float2*)(xb + (2 * pr) * 28 + 2 * pc);
    float2 bot = *(const float2*)(xb + (2 * pr + 1) * 28 + 2 * pc);
    float s0, c0, s1, c1, s2, c2, s3, c3;
    __sincosf(0.5f * top.x, &s0, &c0);
    __sincosf(0.5f * top.y, &s1, &c1);
    __sincosf(0.5f * bot.x, &s2, &c2);
    __sincosf(0.5f * bot.y, &s3, &c3);

    float p0 = c0 * c1, p1 = c0 * s1, p2 = s0 * c1, p3 = s0 * s1;
    float q0 = c2 * c3, q1 = c2 * s3, q2 = s2 * c3, q3 = s2 * s3;

    float P[10] = {p0 * p0, p0 * p1, p0 * p2, p0 * p3, p1 * p1,
                   p1 * p2, p1 * p3, p2 * p2, p2 * p3, p3 * p3};
    float Q[10] = {q0 * q0, q0 * q1, q0 * q2, q0 * q3, q1 * q1,
                   q1 * q2, q1 * q3, q2 * q2, q2 * q3, q3 * q3};

    float e[4];
#pragma unroll
    for (int w = 0; w < 4; ++w) {
      float acc = 0.f;
#pragma unroll
      for (int a = 0; a < 10; ++a) {
        const float* row = C + (w * 10 + a) * 10;
        float tt = row[0] * Q[0] + row[1] * Q[1] + row[2] * Q[2] +
                   row[3] * Q[3] + row[4] * Q[4] + row[5] * Q[5] +
                   row[6] * Q[6] + row[7] * Q[7] + row[8] * Q[8] +
                   row[9] * Q[9];
        acc += P[a] * tt;
      }
      e[w] = acc;
    }

    float4 f = make_float4(e[0], e[1], e[2], e[3]);
#pragma unroll
    for (int c = 0; c < 10; ++c) {
      float4 w = W4[c * NPATCH + p];
      lg[c] = f.x * w.x + f.y * w.y + f.z * w.z + f.w * w.w;
    }
  }

  // 64-lane butterfly per wave
#pragma unroll
  for (int off = 32; off >= 1; off >>= 1)
#pragma unroll
    for (int c = 0; c < 10; ++c)
      lg[c] += __shfl_xor(lg[c], off, 64);

  // fold 4 waves via LDS
  __shared__ float red[4][10];
  int wave = threadIdx.x >> 6;
  int lane = threadIdx.x & 63;
  if (lane == 0) {
#pragma unroll
    for (int c = 0; c < 10; ++c) red[wave][c] = lg[c];
  }
  __syncthreads();

  if (threadIdx.x == 0) {
    float L[10], m = -1e30f;
#pragma unroll
    for (int c = 0; c < 10; ++c) {
      L[c] = red[0][c] + red[1][c] + red[2][c] + red[3][c] + bias[c];
      m = fmaxf(m, L[c]);
    }
    float ssum = 0.f;
#pragma unroll
    for (int c = 0; c < 10; ++c) ssum += __expf(L[c] - m);
    float ls = m + __logf(ssum);
#pragma unroll
    for (int c = 0; c < 10; ++c) out[b * 10 + c] = L[c] - ls;
  }
}

extern "C" void kernel_launch(void* const* d_in, const int* in_sizes, int n_in,
                              void* d_out, int out_size, void* d_ws, size_t ws_size,
                              hipStream_t stream) {
  const float* x    = (const float*)d_in[0];  // (B,1,28,28)
  const float* vp   = (const float*)d_in[1];  // (3,8)
  const float* W    = (const float*)d_in[2];  // (10,784)
  const float* bias = (const float*)d_in[3];  // (10,)
  float* out = (float*)d_out;

  int B = in_sizes[0] / 784;

  float* Cws = (float*)d_ws;  // 400 floats (1.6 KB) — only d_ws use

  qc_build_C<<<1, 64, 0, stream>>>(vp, Cws);

  qc_fused<<<B, 256, 0, stream>>>(x, Cws, (const float4*)W, bias, out);
}

// Round 5
// 102.039 us; speedup vs baseline: 1.0088x; 1.0088x over previous
//
#include <hip/hip_runtime.h>
#include <hip/hip_bf16.h>

// Quanvolution classifier, round 5: two-phase (sim -> feats -> head),
// padded C table (40 rows x 16 floats), 2 patches/thread, all C reads as
// aligned float4s (pad columns are zero so they contribute nothing).
//
// Algebra (validated rounds 1-3): variational circuit is data-independent =>
// U (16x16 complex) fixed. Encoder state s = p (x) q (real product state).
//   e_w = s^T M_w s,  M_w = Re(U^dag Z_w U),
//   e_w = sum_{a,b in 10} C_w[a][b] P_a Q_b   (pair-product folding)
//
// Wire convention: wire 0 = MSB; i = 4*jp + jq, s[i] = p[jp]*q[jq],
// p = (c0c1, c0s1, s0c1, s0s1), q = (c2c3, c2s3, s2c3, s2s3).

#define NPATCH 196

// ---------------- kernel 1: vparams -> U -> M_w -> Cpad (40x16) ----------
__global__ void qc_build_C(const float* __restrict__ vp,
                           float* __restrict__ Cout) {
  __shared__ float Ur[16][16];   // [i][j]
  __shared__ float Ui[16][16];
  __shared__ float M[4][16][16];
  int t = threadIdx.x;

  if (t < 16) {
    float sr[16], si[16];
#pragma unroll
    for (int i = 0; i < 16; ++i) { sr[i] = 0.f; si[i] = 0.f; }
    sr[t] = 1.f;

    for (int l = 0; l < 3; ++l) {
#pragma unroll
      for (int w = 0; w < 4; ++w) {
        float thy = vp[l * 8 + (w % 8)];
        float thz = vp[l * 8 + ((w + 1) % 8)];
        float cy, sy, cz, sz;
        __sincosf(0.5f * thy, &sy, &cy);
        __sincosf(0.5f * thz, &sz, &cz);
        const int bit = 8 >> w;
        // RY
#pragma unroll
        for (int i = 0; i < 16; ++i) {
          if (!(i & bit)) {
            int i1 = i | bit;
            float a0r = sr[i], a0i = si[i], a1r = sr[i1], a1i = si[i1];
            sr[i]  = cy * a0r - sy * a1r;  si[i]  = cy * a0i - sy * a1i;
            sr[i1] = sy * a0r + cy * a1r;  si[i1] = sy * a0i + cy * a1i;
          }
        }
        // RZ: amp0 *= e^{-i thz/2}, amp1 *= e^{+i thz/2}
#pragma unroll
        for (int i = 0; i < 16; ++i) {
          float r = sr[i], m = si[i];
          if (i & bit) { sr[i] = r * cz - m * sz; si[i] = m * cz + r * sz; }
          else         { sr[i] = r * cz + m * sz; si[i] = m * cz - r * sz; }
        }
      }
      // CX ring
#pragma unroll
      for (int w = 0; w < 4; ++w) {
        const int cbit = 8 >> w;
        const int tbit = 8 >> ((w + 1) & 3);
#pragma unroll
        for (int i = 0; i < 16; ++i) {
          if ((i & cbit) && !(i & tbit)) {
            int i1 = i | tbit;
            float tr = sr[i], ti = si[i];
            sr[i] = sr[i1]; si[i] = si[i1];
            sr[i1] = tr;    si[i1] = ti;
          }
        }
      }
    }
#pragma unroll
    for (int i = 0; i < 16; ++i) { Ur[i][t] = sr[i]; Ui[i][t] = si[i]; }
  }
  __syncthreads();

  // M_w[r][c] = sum_i sgn_w(i) * (Ur[i][r]Ur[i][c] + Ui[i][r]Ui[i][c])
  for (int e = t; e < 1024; e += 64) {
    int w = e >> 8, r = (e >> 4) & 15, c = e & 15;
    float acc = 0.f;
#pragma unroll
    for (int i = 0; i < 16; ++i) {
      float sgn = ((i >> (3 - w)) & 1) ? -1.f : 1.f;
      acc += sgn * (Ur[i][r] * Ur[i][c] + Ui[i][r] * Ui[i][c]);
    }
    M[w][r][c] = acc;
  }
  __syncthreads();

  const int pj1[10] = {0, 0, 0, 0, 1, 1, 1, 2, 2, 3};
  const int pj2[10] = {0, 1, 2, 3, 1, 2, 3, 2, 3, 3};
  // padded layout: Cout[(w*10+a)*16 + b], b in [0,16), cols 10..15 zero
  for (int e = t; e < 640; e += 64) {
    int row = e >> 4;          // w*10 + a
    int col = e & 15;          // b (or pad)
    float v = 0.f;
    if (col < 10) {
      int w = row / 10;
      int a = row - w * 10;
      int j1 = pj1[a], j2 = pj2[a], k1 = pj1[col], k2 = pj2[col];
      v = M[w][4 * j1 + k1][4 * j2 + k2];
      if (k1 != k2) v += M[w][4 * j1 + k2][4 * j2 + k1];
      if (j1 != j2) {
        v += M[w][4 * j2 + k1][4 * j1 + k2];
        if (k1 != k2) v += M[w][4 * j2 + k2][4 * j1 + k1];
      }
    }
    Cout[e] = v;
  }
}

// ---------------- kernel 2: quadratic form, 2 patches/thread -------------
// Thread handles patches (2r, 2r+1) of sample b — same 2-row pixel strip,
// so pixel input = two aligned float4 loads; C rows amortize over both.
__global__ __launch_bounds__(256) void qc_sim(const float* __restrict__ x,
                                              const float4* __restrict__ C4,
                                              float4* __restrict__ feats,
                                              int totalPairs) {
  int idx = blockIdx.x * 256 + threadIdx.x;
  if (idx >= totalPairs) return;
  int b = idx / 98;
  int r = idx - b * 98;        // pair index: patches 2r, 2r+1
  int pr = r / 7;              // patch row (0..13)
  int g  = r - pr * 7;         // pair column (0..6); pc0 = 2g
  const float* xb = x + (size_t)b * 784;

  // pixel strip: rows 2pr, 2pr+1, float columns 4g..4g+3 (16B-aligned)
  float4 t4 = *(const float4*)(xb + 56 * pr + 4 * g);
  float4 b4 = *(const float4*)(xb + 56 * pr + 28 + 4 * g);

  float P0[10], Q0[10], P1[10], Q1[10];
  {
    float s0, c0, s1, c1, s2, c2, s3, c3;
    __sincosf(0.5f * t4.x, &s0, &c0);
    __sincosf(0.5f * t4.y, &s1, &c1);
    __sincosf(0.5f * b4.x, &s2, &c2);
    __sincosf(0.5f * b4.y, &s3, &c3);
    float p0 = c0 * c1, p1 = c0 * s1, p2 = s0 * c1, p3 = s0 * s1;
    float q0 = c2 * c3, q1 = c2 * s3, q2 = s2 * c3, q3 = s2 * s3;
    P0[0] = p0 * p0; P0[1] = p0 * p1; P0[2] = p0 * p2; P0[3] = p0 * p3;
    P0[4] = p1 * p1; P0[5] = p1 * p2; P0[6] = p1 * p3; P0[7] = p2 * p2;
    P0[8] = p2 * p3; P0[9] = p3 * p3;
    Q0[0] = q0 * q0; Q0[1] = q0 * q1; Q0[2] = q0 * q2; Q0[3] = q0 * q3;
    Q0[4] = q1 * q1; Q0[5] = q1 * q2; Q0[6] = q1 * q3; Q0[7] = q2 * q2;
    Q0[8] = q2 * q3; Q0[9] = q3 * q3;
  }
  {
    float s0, c0, s1, c1, s2, c2, s3, c3;
    __sincosf(0.5f * t4.z, &s0, &c0);
    __sincosf(0.5f * t4.w, &s1, &c1);
    __sincosf(0.5f * b4.z, &s2, &c2);
    __sincosf(0.5f * b4.w, &s3, &c3);
    float p0 = c0 * c1, p1 = c0 * s1, p2 = s0 * c1, p3 = s0 * s1;
    float q0 = c2 * c3, q1 = c2 * s3, q2 = s2 * c3, q3 = s2 * s3;
    P1[0] = p0 * p0; P1[1] = p0 * p1; P1[2] = p0 * p2; P1[3] = p0 * p3;
    P1[4] = p1 * p1; P1[5] = p1 * p2; P1[6] = p1 * p3; P1[7] = p2 * p2;
    P1[8] = p2 * p3; P1[9] = p3 * p3;
    Q1[0] = q0 * q0; Q1[1] = q0 * q1; Q1[2] = q0 * q2; Q1[3] = q0 * q3;
    Q1[4] = q1 * q1; Q1[5] = q1 * q2; Q1[6] = q1 * q3; Q1[7] = q2 * q2;
    Q1[8] = q2 * q3; Q1[9] = q3 * q3;
  }

  float e0[4], e1[4];
#pragma unroll
  for (int w = 0; w < 4; ++w) {
    float a0 = 0.f, a1 = 0.f;
#pragma unroll
    for (int a = 0; a < 10; ++a) {
      int base = (w * 10 + a) * 4;   // float4 index into padded 16-float row
      float4 r0 = C4[base];
      float4 r1 = C4[base + 1];
      float4 r2 = C4[base + 2];      // only .x,.y meaningful; .z,.w are 0
      float tt0 = r0.x * Q0[0] + r0.y * Q0[1] + r0.z * Q0[2] + r0.w * Q0[3]
                + r1.x * Q0[4] + r1.y * Q0[5] + r1.z * Q0[6] + r1.w * Q0[7]
                + r2.x * Q0[8] + r2.y * Q0[9];
      float tt1 = r0.x * Q1[0] + r0.y * Q1[1] + r0.z * Q1[2] + r0.w * Q1[3]
                + r1.x * Q1[4] + r1.y * Q1[5] + r1.z * Q1[6] + r1.w * Q1[7]
                + r2.x * Q1[8] + r2.y * Q1[9];
      a0 += P0[a] * tt0;
      a1 += P1[a] * tt1;
    }
    e0[w] = a0; e1[w] = a1;
  }

  float4* fb = feats + (size_t)b * NPATCH + 2 * r;
  fb[0] = make_float4(e0[0], e0[1], e0[2], e0[3]);
  fb[1] = make_float4(e1[0], e1[1], e1[2], e1[3]);
}

// ---------------- kernel 3: head (feats @ W^T + b, log_softmax) ----------
__global__ __launch_bounds__(64) void qc_head(const float4* __restrict__ feats,
                                              const float4* __restrict__ W4,
                                              const float* __restrict__ bias,
                                              float* __restrict__ out) {
  int b = blockIdx.x;
  int lane = threadIdx.x;
  float lg[10];
#pragma unroll
  for (int c = 0; c < 10; ++c) lg[c] = 0.f;

  const float4* fb = feats + (size_t)b * NPATCH;
#pragma unroll
  for (int k = 0; k < 4; ++k) {
    int t = lane + 64 * k;
    if (t < NPATCH) {
      float4 f = fb[t];
#pragma unroll
      for (int c = 0; c < 10; ++c) {
        float4 w = W4[c * NPATCH + t];
        lg[c] += f.x * w.x + f.y * w.y + f.z * w.z + f.w * w.w;
      }
    }
  }
#pragma unroll
  for (int off = 32; off >= 1; off >>= 1)
#pragma unroll
    for (int c = 0; c < 10; ++c)
      lg[c] += __shfl_xor(lg[c], off, 64);

  if (lane == 0) {
    float L[10], m = -1e30f;
#pragma unroll
    for (int c = 0; c < 10; ++c) { L[c] = lg[c] + bias[c]; m = fmaxf(m, L[c]); }
    float ssum = 0.f;
#pragma unroll
    for (int c = 0; c < 10; ++c) ssum += __expf(L[c] - m);
    float ls = m + __logf(ssum);
#pragma unroll
    for (int c = 0; c < 10; ++c) out[b * 10 + c] = L[c] - ls;
  }
}

extern "C" void kernel_launch(void* const* d_in, const int* in_sizes, int n_in,
                              void* d_out, int out_size, void* d_ws, size_t ws_size,
                              hipStream_t stream) {
  const float* x    = (const float*)d_in[0];  // (B,1,28,28)
  const float* vp   = (const float*)d_in[1];  // (3,8)
  const float* W    = (const float*)d_in[2];  // (10,784)
  const float* bias = (const float*)d_in[3];  // (10,)
  float* out = (float*)d_out;

  int B = in_sizes[0] / 784;

  float*  Cws   = (float*)d_ws;                   // 640 floats (2.56 KB, padded)
  float4* feats = (float4*)((char*)d_ws + 4096);  // B*196 float4 (12.8 MB)

  qc_build_C<<<1, 64, 0, stream>>>(vp, Cws);

  int totalPairs = B * 98;  // 2 patches per thread
  qc_sim<<<(totalPairs + 255) / 256, 256, 0, stream>>>(x, (const float4*)Cws,
                                                       feats, totalPairs);

  qc_head<<<B, 64, 0, stream>>>(feats, (const float4*)W, bias, out);
}